// Round 4
// baseline (348.205 us; speedup 1.0000x reference)
//
#include <hip/hip_runtime.h>

#define SEQ 512
#define NB  512
#define NT  96

typedef float f2 __attribute__((ext_vector_type(2)));

// One wave (64 lanes) per batch chain. Lane l owns tag columns l and 64+l
// (upper 32 columns live in lanes 0..31; lanes 32..63 compute a harmless
// duplicate in .y that is never stored or reduced).
//
// Linear-domain forward recursion (alpha kept as A = exp(alpha) * 2^K):
//   A'[j] = (sum_k A[k] * E[k][j]) * w[j] * 2^-k_i
// E = exp(T) in 192 VGPRs, w = exp(em) prefetched+exp'd off the critical
// path, 2^-k_i exact rescale from exponent bits of A[0]. No barriers, no
// transcendentals, and only one LDS round-trip on the 511-step serial chain.
__launch_bounds__(64, 1)
__global__ void crf_wave(const float* __restrict__ logits,
                         const int*   __restrict__ tags,
                         const int*   __restrict__ mask,
                         const float* __restrict__ trans,
                         const float* __restrict__ startt,
                         const float* __restrict__ endt,
                         float* __restrict__ out)
{
    const int b  = blockIdx.x;
    const int l  = threadIdx.x;          // 0..63
    const int l2 = 64 + (l & 31);        // second column (meaningful for l<32)
    const float* em = logits + (size_t)b * SEQ * NT;

    __shared__ __align__(16) float e_buf[2][NT];
    __shared__ int tg_s[SEQ];
    __shared__ int mk_s[SEQ];

    for (int i = l; i < SEQ; i += 64) {
        tg_s[i] = tags[(size_t)b * SEQ + i];
        mk_s[i] = mask[(size_t)b * SEQ + i];
    }

    // E-table columns: colp[k] = (exp(T[k][l]), exp(T[k][l2]))
    f2 colp[NT];
#pragma unroll
    for (int k = 0; k < NT; ++k) {
        colp[k].x = __expf(trans[k * NT + l]);
        colp[k].y = __expf(trans[k * NT + l2]);
    }

    // init: A0 = exp(start + em[0]); K = 0
    f2 A;
    A.x = __expf(startt[l]  + em[l]);
    A.y = __expf(startt[l2] + em[l2]);
    int K = 0;

    e_buf[0][l] = A.x;
    if (l < 32) e_buf[0][l2] = A.y;

    // emission prefetch queue (rows i+1, i+2, i+3)
    f2 emq1, emq2, emq3;
    emq1.x = em[1 * NT + l]; emq1.y = em[1 * NT + l2];
    emq2.x = em[2 * NT + l]; emq2.y = em[2 * NT + l2];
    emq3.x = em[3 * NT + l]; emq3.y = em[3 * NT + l2];
    __syncthreads();   // once, outside the loop (single wave, near-free)

    for (int i = 1; i < SEQ; ++i) {
        // w for this step (off critical path: used only at the end)
        f2 w;
        w.x = __expf(emq1.x);
        w.y = __expf(emq1.y);

        // prefetch emission row i+3
        f2 emn; emn.x = 0.f; emn.y = 0.f;
        if (i + 3 < SEQ) {
            emn.x = em[(i + 3) * NT + l];
            emn.y = em[(i + 3) * NT + l2];
        }
        const int mk = mk_s[i];

        // matvec: v[j] = sum_k A[k] * E[k][j]  (broadcast b128 reads)
        const float4* e4 = (const float4*)e_buf[(i + 1) & 1];
        f2 a0, a1, a2, a3;
        a0.x=0.f;a0.y=0.f;a1.x=0.f;a1.y=0.f;a2.x=0.f;a2.y=0.f;a3.x=0.f;a3.y=0.f;
        float A0prev = 0.f;
#pragma unroll
        for (int q = 0; q < 24; ++q) {
            const float4 ev = e4[q];
            if (q == 0) A0prev = ev.x;      // uniform: previous A[0]
            a0 += colp[4 * q + 0] * ev.x;   // v_pk_fma_f32
            a1 += colp[4 * q + 1] * ev.y;
            a2 += colp[4 * q + 2] * ev.z;
            a3 += colp[4 * q + 3] * ev.w;
        }
        const f2 v = (a0 + a1) + (a2 + a3);

        // exact power-of-2 rescale from exponent of A[0] (uniform across wave)
        const unsigned eb = __float_as_uint(A0prev);
        const int expo = (int)((eb >> 23) & 0xFFu);
        const float s = __uint_as_float((unsigned)(247 - expo) << 23); // 2^(120-expo)
        const int ki = expo - 120;

        const f2 wv = w * s;
        const f2 An = v * wv;
        if (mk) { A = An; K += ki; }

        float* wb = e_buf[i & 1];
        wb[l] = A.x;
        if (l < 32) wb[l2] = A.y;

        emq1 = emq2; emq2 = emq3; emq3 = emn;
    }

    // ---- denominator: log(sum_j A[j]*exp(end[j])) + K*ln2 ----
    float pd = A.x * __expf(endt[l]);
    if (l < 32) pd += A.y * __expf(endt[l2]);

    // ---- numerator partials ----
    float pn = 0.f;
    for (int i = 1 + l; i < SEQ; i += 64) {
        if (mk_s[i]) {
            const int tp = tg_s[i - 1], tc = tg_s[i];
            pn += trans[tp * NT + tc] + em[i * NT + tc];
        }
    }
    int cnt = 0;
    for (int i = l; i < SEQ; i += 64) cnt += mk_s[i];

#pragma unroll
    for (int m = 32; m >= 1; m >>= 1) {
        pd  += __shfl_xor(pd, m, 64);
        pn  += __shfl_xor(pn, m, 64);
        cnt += __shfl_xor(cnt, m, 64);
    }

    if (l == 0) {
        const float denom = __logf(pd) + (float)K * 0.69314718055994531f;
        const float num = startt[tg_s[0]] + em[tg_s[0]]
                        + endt[tg_s[cnt - 1]] + pn;
        atomicAdd(out, num - denom);
    }
}

extern "C" void kernel_launch(void* const* d_in, const int* in_sizes, int n_in,
                              void* d_out, int out_size, void* d_ws, size_t ws_size,
                              hipStream_t stream)
{
    const float* logits = (const float*)d_in[0];
    const int*   tags   = (const int*)  d_in[1];
    const int*   mask   = (const int*)  d_in[2];
    const float* trans  = (const float*)d_in[3];
    const float* startt = (const float*)d_in[4];
    const float* endt   = (const float*)d_in[5];
    float* out = (float*)d_out;

    hipMemsetAsync(out, 0, out_size * sizeof(float), stream);
    crf_wave<<<NB, 64, 0, stream>>>(logits, tags, mask, trans,
                                    startt, endt, out);
}

// Round 5
// 253.971 us; speedup vs baseline: 1.3710x; 1.3710x over previous
//
#include <hip/hip_runtime.h>

#define SEQ 512
#define NB  512
#define NT  96

typedef float f2 __attribute__((ext_vector_type(2)));

// One block = one batch chain, 96 threads (thread j owns tag-column j).
// Linear-domain forward recursion (A = exp(alpha) * 2^K):
//   A'[j] = (sum_k A[k]*E[k][j]) * exp(em[i][j]) * 2^-ki
// E-table packed along K: colp[m] = (E[2m][j], E[2m+1][j]) -> 96 VGPRs,
// inner loop = 48 v_pk_fma_f32. No transcendentals on the serial chain,
// ONE barrier per step, 4-slot LDS rotation for the state exchange.
__launch_bounds__(NT, 1)
__global__ void crf_lin96(const float* __restrict__ logits,
                          const int*   __restrict__ tags,
                          const int*   __restrict__ mask,
                          const float* __restrict__ trans,
                          const float* __restrict__ startt,
                          const float* __restrict__ endt,
                          float* __restrict__ out)
{
    const int b = blockIdx.x;
    const int j = threadIdx.x;              // 0..95
    const float* em = logits + (size_t)b * SEQ * NT;

    __shared__ __align__(16) float Abuf[4][NT];
    __shared__ float red[NT];
    __shared__ float num_red[NT];
    __shared__ int tg_s[SEQ];
    __shared__ int mk_s[SEQ];

    for (int i = j; i < SEQ; i += NT) {
        tg_s[i] = tags[(size_t)b * SEQ + i];
        mk_s[i] = mask[(size_t)b * SEQ + i];
    }

    // E-table column j, K-packed: colp[m] = (exp(T[2m][j]), exp(T[2m+1][j]))
    f2 colp[48];
#pragma unroll
    for (int m = 0; m < 48; ++m) {
        colp[m].x = __expf(trans[(2 * m + 0) * NT + j]);
        colp[m].y = __expf(trans[(2 * m + 1) * NT + j]);
    }

    float A = __expf(startt[j] + em[j]);    // A0 = exp(start + em[0]), K = 0
    int K = 0;
    Abuf[0][j] = A;

    float emq1 = em[1 * NT + j];
    float emq2 = em[2 * NT + j];
    float emq3 = em[3 * NT + j];
    __syncthreads();

    for (int i = 1; i < SEQ; ++i) {
        const float w = __expf(emq1);       // off critical path
        float emn = 0.f;
        if (i + 3 < SEQ) emn = em[(i + 3) * NT + j];
        const int mk = mk_s[i];

        const float4* e4 = (const float4*)Abuf[(i - 1) & 3];
        f2 acc[8];
#pragma unroll
        for (int m = 0; m < 8; ++m) { acc[m].x = 0.f; acc[m].y = 0.f; }
        float A0prev = 0.f;
#pragma unroll
        for (int q = 0; q < 24; ++q) {
            const float4 ev = e4[q];        // broadcast b128, conflict-free
            if (q == 0) A0prev = ev.x;
            f2 lo; lo.x = ev.x; lo.y = ev.y;
            f2 hi; hi.x = ev.z; hi.y = ev.w;
            acc[(2 * q + 0) & 7] += lo * colp[2 * q + 0];   // v_pk_fma_f32
            acc[(2 * q + 1) & 7] += hi * colp[2 * q + 1];
        }
        const f2 t = ((acc[0] + acc[1]) + (acc[2] + acc[3]))
                   + ((acc[4] + acc[5]) + (acc[6] + acc[7]));
        const float v = t.x + t.y;

        // exact power-of-2 rescale from exponent of A_prev[0] (wave-uniform)
        const unsigned eb = __float_as_uint(A0prev);
        const int expo = (int)((eb >> 23) & 0xFFu);
        const float s = __uint_as_float((unsigned)(247 - expo) << 23); // 2^(120-expo)
        const int ki = expo - 120;

        const float An = v * (w * s);
        if (mk) { A = An; K += ki; }
        Abuf[i & 3][j] = A;
        emq1 = emq2; emq2 = emq3; emq3 = emn;
        __syncthreads();                    // the ONLY barrier per step
    }

    // ---- denominator: log(sum_j A[j]*exp(end[j])) + K*ln2 ----
    red[j] = A * __expf(endt[j]);

    // ---- numerator partials ----
    float pn = 0.f;
    for (int i = 1 + j; i < SEQ; i += NT) {
        if (mk_s[i]) {
            const int tp = tg_s[i - 1], tc = tg_s[i];
            pn += trans[tp * NT + tc] + em[i * NT + tc];
        }
    }
    num_red[j] = pn;
    __syncthreads();

    if (j == 0) {
        float pd = 0.f;
        for (int k = 0; k < NT; ++k) pd += red[k];
        const float denom = __logf(pd) + (float)K * 0.69314718055994531f;

        float num = startt[tg_s[0]] + em[tg_s[0]];
        for (int k = 0; k < NT; ++k) num += num_red[k];
        int cnt = 0;
        for (int i = 0; i < SEQ; ++i) cnt += mk_s[i];
        num += endt[tg_s[cnt - 1]];

        atomicAdd(out, num - denom);
    }
}

extern "C" void kernel_launch(void* const* d_in, const int* in_sizes, int n_in,
                              void* d_out, int out_size, void* d_ws, size_t ws_size,
                              hipStream_t stream)
{
    const float* logits = (const float*)d_in[0];
    const int*   tags   = (const int*)  d_in[1];
    const int*   mask   = (const int*)  d_in[2];
    const float* trans  = (const float*)d_in[3];
    const float* startt = (const float*)d_in[4];
    const float* endt   = (const float*)d_in[5];
    float* out = (float*)d_out;

    hipMemsetAsync(out, 0, out_size * sizeof(float), stream);
    crf_lin96<<<NB, NT, 0, stream>>>(logits, tags, mask, trans,
                                     startt, endt, out);
}